// Round 21
// baseline (77.394 us; speedup 1.0000x reference)
//
#include <hip/hip_runtime.h>

#define T_LEN 65536
#define C_CH 8
#define CLEN 16
#define NB 16
#define WIN (CLEN * NB)          // 256 steps per window
#define NBLK 2048                // 32 whi x 8 ch x 8 slot; 1 window per wave
#define SCANW 6                  // 384 bits scanned per window
#define MAXB 32                  // step-block size

typedef short bf16x8 __attribute__((ext_vector_type(8)));
typedef float f32x4 __attribute__((ext_vector_type(4)));
typedef unsigned int uint;
typedef uint u32x4 __attribute__((ext_vector_type(4)));
typedef unsigned long long u64;

#define MFMA32 __builtin_amdgcn_mfma_f32_16x16x32_bf16

#define SC_RZ 1.4426950408889634f   // log2(e): folded into r/z rows
#define SC_N  2.8853900817779268f   // 2*log2(e): folded into n rows

__device__ __forceinline__ uint f2bf(float f) {           // RNE float->bf16
    uint u = __float_as_uint(f);
    return (u + 0x7FFFu + ((u >> 16) & 1u)) >> 16;
}
__device__ __forceinline__ uint pk(float a, float b) {
    return f2bf(a) | (f2bf(b) << 16);
}
__device__ __forceinline__ uint cvtpk(float lo, float hi) {
    uint r;
    asm("v_cvt_pk_bf16_f32 %0, %1, %2" : "=v"(r) : "v"(lo), "v"(hi));
    return r;
}
// builtin exp2: compiler knows TRANS hazard (inline-asm version was R7's bug)
__device__ __forceinline__ float expneg(float x) { return __builtin_amdgcn_exp2f(-x); }
__device__ __forceinline__ bf16x8 mk8(uint a, uint b, uint c, uint d) {
    union { uint u[4]; bf16x8 v; } x;
    x.u[0] = a; x.u[1] = b; x.u[2] = c; x.u[3] = d;
    return x.v;
}
__device__ __forceinline__ bf16x8 q2b(u32x4 q) {
    union { u32x4 q; bf16x8 b; } u; u.q = q; return u.b;
}
__device__ __forceinline__ float rcpf(float v) { return __builtin_amdgcn_rcpf(v); }

// largest set-bit position p <= X in the 384-bit window mask; -1 if none.
// Wave-uniform inputs -> uniform branches, no divergence cost.
__device__ __forceinline__ int prev_start_le(u64 w0, u64 w1, u64 w2, u64 w3,
                                             u64 w4, u64 w5, int X) {
    auto msk = [](u64 w, int base, int X) -> u64 {
        if (X < base) return 0ull;
        int r = X - base;
        u64 m = (r >= 63) ? ~0ull : ((1ull << (r + 1)) - 1ull);
        return w & m;
    };
    u64 m5 = msk(w5, 320, X), m4 = msk(w4, 256, X), m3 = msk(w3, 192, X);
    u64 m2 = msk(w2, 128, X), m1 = msk(w1, 64, X),  m0 = msk(w0, 0, X);
    if (m5) return 320 + 63 - __builtin_clzll(m5);
    if (m4) return 256 + 63 - __builtin_clzll(m4);
    if (m3) return 192 + 63 - __builtin_clzll(m3);
    if (m2) return 128 + 63 - __builtin_clzll(m2);
    if (m1) return  64 + 63 - __builtin_clzll(m1);
    if (m0) return        63 - __builtin_clzll(m0);
    return -1;
}

// (64,2) + AGPR pinning + minimax repartition (R20, 74.9us). Single knob this
// round: escalation ladder now starts at L0 (perfect-pack attempt) instead of
// L0+1 -> Lmax hits the ~16 floor when the start pattern allows it.
__global__ __launch_bounds__(64, 2) void gru_mfma(
    const float* __restrict__ x,     // (T,10,8)
    const int*   __restrict__ cg,    // (T,8)
    const int*   __restrict__ cs,    // (T,8)
    const float* __restrict__ W_ih,  // (8,192,4)
    const float* __restrict__ W_hh,  // (8,192,64)
    const float* __restrict__ b_ih,  // (8,192)
    const float* __restrict__ b_hh,  // (8,192)
    const float* __restrict__ W_out, // (8,1,64)
    const float* __restrict__ b_out, // (8,)
    float* __restrict__ y)           // (T,)
{
    __shared__ u64 stw[SCANW], acw[SCANW];
    __shared__ int sb[NB + 1];
    __shared__ float yw[NB][MAXB + 1];
    __shared__ uint2 bxl[MAXB][NB];

    const int lane = threadIdx.x;
    const int l15 = lane & 15, l4 = lane >> 4;
    // decode: all 8 channels of one time-slot share an XCD (bid%8 = w%8)
    const int slot = blockIdx.x & 7;
    const int c    = (blockIdx.x >> 3) & 7;
    const int whi  = blockIdx.x >> 6;        // 0..31
    const int w    = whi * 8 + slot;         // window id 0..255
    const int RB   = w * WIN;

    // ---- cooperative scan of cs/cg bits ----
    for (int rr = 0; rr < SCANW; ++rr) {
        int t = RB + rr * 64 + lane;
        int sv = 0, av = 0;
        if (t < T_LEN) { sv = cs[t * C_CH + c]; av = cg[t * C_CH + c]; }
        u64 m1 = __ballot(sv == 1);
        u64 m2 = __ballot(av == 1);
        if (lane == 0) { stw[rr] = m1; acw[rr] = m2; }
    }
    __syncthreads();

    // ---- grid boundaries (also the fallback): sb[k] = first start >= RB+k*CLEN ----
    if (lane <= NB) {
        int rel = lane * CLEN;
        int q = rel >> 6, r0 = rel & 63;
        u64 m = stw[q] >> r0;
        int pos = -1;
        if (m) pos = rel + __ffsll(m) - 1;
        else {
            for (int q2 = q + 1; q2 < SCANW; ++q2)
                if (stw[q2]) { pos = (q2 << 6) + __ffsll(stw[q2]) - 1; break; }
        }
        int Sa;
        if (pos >= 0) Sa = RB + pos;
        else {  // ultra-rare fallback: serial scan past region
            int t = RB + SCANW * 64;
            while (t < T_LEN && cs[t * C_CH + c] != 1) ++t;
            Sa = t;
        }
        sb[lane] = min(Sa, T_LEN);
    }
    __syncthreads();

    // ---- minimax rebalance of interior boundaries (load-balance 16 chunks) ----
    {
        const int rel0  = sb[0]  - RB;
        const int rel16 = sb[NB] - RB;
        if (rel16 > rel0 && rel16 <= SCANW * 64 && rel0 < SCANW * 64) {
            const u64 w0 = stw[0], w1 = stw[1], w2 = stw[2];
            const u64 w3 = stw[3], w4 = stw[4], w5 = stw[5];
            const int span = rel16 - rel0;
            const int L0 = (span + 15) >> 4;
            int myb = 0;
            bool done = false;
#pragma unroll
            for (int a = 0; a < 5; ++a) {
                const int L = L0 + ((a == 0) ? 0 : (a == 1) ? 1 : (a == 2) ? 3
                                   : (a == 3) ? 6 : 10);
                if (done) continue;
                int prev = rel0, mybt = 0;
                bool ok = true;
                for (int k = 1; k <= 15; ++k) {
                    int bk;
                    if (prev >= rel16) bk = rel16;
                    else {
                        int cap = min(prev + L, rel16);
                        int nb = prev_start_le(w0, w1, w2, w3, w4, w5, cap);
                        if (nb <= prev) { ok = false; nb = prev; }
                        bk = nb;
                    }
                    if (lane == k) mybt = bk;
                    prev = bk;
                }
                ok = ok && (rel16 - prev <= L);
                if (ok) { done = true; myb = mybt; }
            }
            __syncthreads();
            if (done && lane >= 1 && lane <= 15) sb[lane] = RB + myb;
        }
    }
    __syncthreads();

    const int S = sb[l15];
    const int len = sb[l15 + 1] - S;
    int Lmax = len;
#pragma unroll
    for (int o = 1; o < 16; o <<= 1) Lmax = max(Lmax, __shfl_xor(Lmax, o));

    // ---- A-fragments -> AGPRs (window constants), log2e pre-scaled ----
    const float* Wc = W_hh + c * 192 * 64;
    u32x4 AhA[12][2];
#pragma unroll
    for (int tm = 0; tm < 12; ++tm) {
        const float sc = (tm < 8) ? SC_RZ : SC_N;
#pragma unroll
        for (int kt = 0; kt < 2; ++kt) {
            const float* p = Wc + (16 * tm + l15) * 64 + 32 * kt + 4 * l4;
            float4 a = *(const float4*)p;
            float4 b = *(const float4*)(p + 16);
            AhA[tm][kt] = (u32x4){ pk(a.x * sc, a.y * sc), pk(a.z * sc, a.w * sc),
                                   pk(b.x * sc, b.y * sc), pk(b.z * sc, b.w * sc) };
            asm volatile("" : "+a"(AhA[tm][kt]));   // pin quad into AGPRs
        }
    }
    // W_out as a 13th A-tile (row 0 only): y_t = W_out . h_t via 2 MFMAs
    u32x4 WoA[2];
#pragma unroll
    for (int kt = 0; kt < 2; ++kt) {
        uint d0 = 0, d1 = 0, d2 = 0, d3 = 0;
        if (l15 == 0) {
            const float* wp = W_out + c * 64 + 32 * kt + 4 * l4;
            d0 = pk(wp[0], wp[1]);  d1 = pk(wp[2], wp[3]);
            d2 = pk(wp[16], wp[17]); d3 = pk(wp[18], wp[19]);
        }
        WoA[kt] = (u32x4){ d0, d1, d2, d3 };
        asm volatile("" : "+a"(WoA[kt]));
    }

    // W_ih cols (k=0..3) + ones-column bias at k=4: r/z merged b_ih+b_hh; n: b_ih
    uint Axd[12][2];
#pragma unroll
    for (int tm = 0; tm < 12; ++tm) {
        const float sc = (tm < 8) ? SC_RZ : SC_N;
        int row = 16 * tm + l15;
        uint d0 = 0, d1 = 0;
        if (l4 == 0) {
            float4 wi4 = *(const float4*)(W_ih + (c * 192 + row) * 4);
            d0 = pk(wi4.x * sc, wi4.y * sc);
            d1 = pk(wi4.z * sc, wi4.w * sc);
        } else if (l4 == 1) {
            float bias = (tm < 8) ? (b_ih[c * 192 + row] + b_hh[c * 192 + row]) * SC_RZ
                                  : b_ih[c * 192 + row] * SC_N;
            d0 = f2bf(bias);
        }
        Axd[tm][0] = d0; Axd[tm][1] = d1;
    }
    // n-gate b_hh as fp32 C-init (row = 4*l4+i, column-independent)
    f32x4 bhn4[4];
#pragma unroll
    for (int tn = 0; tn < 4; ++tn) {
        float4 v = *(const float4*)(b_hh + c * 192 + 128 + 16 * tn + 4 * l4);
        bhn4[tn] = (f32x4){v.x * SC_N, v.y * SC_N, v.z * SC_N, v.w * SC_N};
    }
    const float bo = b_out[c];

    // ---- state: bf16 B-frags ONLY (h_old re-expanded by shift; no fp32 h) ----
    uint B0[4], B1[4];
#pragma unroll
    for (int i = 0; i < 4; ++i) { B0[i] = 0u; B1[i] = 0u; }
    const uint bx_c0 = (l4 == 1) ? 0x00003F80u : 0u;  // bf16(1.0) at k=4
    const f32x4 z4 = {0.f, 0.f, 0.f, 0.f};

    for (int s0 = 0; s0 < Lmax; s0 += MAXB) {
        const int Lb = min(MAXB, Lmax - s0);

        // stage Bx payloads: bxl[s][b] = packed bf16 {x1..x4}(t = S_b+s0+s)
        const int npair = Lb * NB;
        for (int p = lane; p < npair; p += 64) {
            int s = p >> 4;
            int t = min(sb[p & 15] + s0 + s, T_LEN - 1);
            const float* xp = x + (size_t)t * 80 + 8 + c;
            bxl[s][p & 15] = make_uint2(pk(xp[0], xp[8]), pk(xp[16], xp[24]));
        }
        // per-lane reset mask for its column, this step-block
        int off = (S - RB) + s0;
        int q = off >> 6, r0 = off & 63;
        u64 w0s = (q < SCANW) ? stw[q] : 0ull;
        u64 w1s = (q + 1 < SCANW) ? stw[q + 1] : 0ull;
        u64 ms = (w0s >> r0) | (r0 ? (w1s << (64 - r0)) : 0ull);
        __syncthreads();

        // Bx register double-buffer: ds_read for step s+1 issues during step s
        uint2 bxn = bxl[0][l15];

        for (int s = 0; s < Lb; ++s) {
            const uint2 bxc = bxn;
            if (s + 1 < Lb) bxn = bxl[s + 1][l15];

            const bool rst = (ms >> s) & 1;
#pragma unroll
            for (int i = 0; i < 4; ++i) {
                B0[i] = rst ? 0u : B0[i];
                B1[i] = rst ? 0u : B1[i];
            }

            const bf16x8 Bx  = mk8((lane < 16) ? bxc.x : bx_c0,
                                   (lane < 16) ? bxc.y : 0u, 0u, 0u);
            const bf16x8 Bh0 = mk8(B0[0], B0[1], B0[2], B0[3]);
            const bf16x8 Bh1 = mk8(B1[0], B1[1], B1[2], B1[3]);

            uint nB[8];
#pragma unroll
            for (int tm = 0; tm < 4; ++tm) {
                const int tz = tm + 4, tn = tm + 8;
                f32x4 ar = MFMA32(mk8(Axd[tm][0], Axd[tm][1], 0u, 0u), Bx, z4, 0, 0, 0);
                ar = MFMA32(q2b(AhA[tm][0]), Bh0, ar, 0, 0, 0);
                ar = MFMA32(q2b(AhA[tm][1]), Bh1, ar, 0, 0, 0);
                f32x4 az = MFMA32(mk8(Axd[tz][0], Axd[tz][1], 0u, 0u), Bx, z4, 0, 0, 0);
                az = MFMA32(q2b(AhA[tz][0]), Bh0, az, 0, 0, 0);
                az = MFMA32(q2b(AhA[tz][1]), Bh1, az, 0, 0, 0);
                f32x4 gx = MFMA32(mk8(Axd[tn][0], Axd[tn][1], 0u, 0u), Bx, z4, 0, 0, 0);
                f32x4 gh = MFMA32(q2b(AhA[tn][0]), Bh0, bhn4[tm], 0, 0, 0);
                gh = MFMA32(q2b(AhA[tn][1]), Bh1, gh, 0, 0, 0);

                float hv[4];
#pragma unroll
                for (int i = 0; i < 4; ++i) {
                    // pre-activations pre-scaled by log2e (r/z) / 2log2e (n).
                    // Joint reciprocal (R15): 5 trans/element.
                    float Dr = 1.f + expneg(ar[i]);
                    float Dz = 1.f + expneg(az[i]);
                    float rc = rcpf(Dr * Dz);
                    float rr = rc * Dz;
                    float zz = rc * Dr;
                    float np2 = fmaf(rr, gh[i], gx[i]);
                    float nn = fmaf(2.f, rcpf(1.f + expneg(np2)), -1.f);
                    // h_old from the bf16 state frag (1-op expand)
                    const uint bd = (tm < 2) ? B0[2 * (tm & 1) + (i >> 1)]
                                             : B1[2 * (tm & 1) + (i >> 1)];
                    const float hold = __uint_as_float((i & 1) ? (bd & 0xFFFF0000u)
                                                               : (bd << 16));
                    float hh = fmaf(zz, hold - nn, nn);
                    hv[i] = hh;
                }
                nB[2 * tm]     = cvtpk(hv[0], hv[1]);
                nB[2 * tm + 1] = cvtpk(hv[2], hv[3]);
            }
            // D-layout == B-layout: tiles 0,1 -> Bh0; 2,3 -> Bh1
            B0[0] = nB[0]; B0[1] = nB[1]; B0[2] = nB[2]; B0[3] = nB[3];
            B1[0] = nB[4]; B1[1] = nB[5]; B1[2] = nB[6]; B1[3] = nB[7];

            // y_t = W_out . h_t via the 13th tile (row 0 -> lanes 0-15, reg 0)
            const bf16x8 Bh0n = mk8(B0[0], B0[1], B0[2], B0[3]);
            const bf16x8 Bh1n = mk8(B1[0], B1[1], B1[2], B1[3]);
            f32x4 y4 = MFMA32(q2b(WoA[0]), Bh0n, z4, 0, 0, 0);
            y4 = MFMA32(q2b(WoA[1]), Bh1n, y4, 0, 0, 0);
            if (lane < 16 && (s0 + s) < len) yw[lane][s] = y4[0];
        }
        __syncthreads();

        // write back: one coalesced atomic row per chunk (channels collide)
        for (int b = 0; b < NB; ++b) {
            int Sb = sb[b];
            int lenb = sb[b + 1] - Sb;
            int sg = s0 + lane;
            if (lane < Lb && sg < lenb) {
                int offa = (Sb - RB) + sg;
                int qa = offa >> 6;
                bool act;
                if (qa < SCANW) act = (acw[qa] >> (offa & 63)) & 1;
                else            act = cg[(Sb + sg) * C_CH + c] == 1;  // rare
                if (act) atomicAdd(&y[Sb + sg], yw[b][lane] + bo);
            }
        }
        __syncthreads();
    }
}

extern "C" void kernel_launch(void* const* d_in, const int* in_sizes, int n_in,
                              void* d_out, int out_size, void* d_ws, size_t ws_size,
                              hipStream_t stream) {
    const float* x     = (const float*)d_in[0];
    const int*   cg    = (const int*)  d_in[1];
    const int*   cs    = (const int*)  d_in[2];
    const float* W_ih  = (const float*)d_in[3];
    const float* W_hh  = (const float*)d_in[4];
    const float* b_ih  = (const float*)d_in[5];
    const float* b_hh  = (const float*)d_in[6];
    const float* W_out = (const float*)d_in[7];
    const float* b_out = (const float*)d_in[8];
    float* y = (float*)d_out;

    hipMemsetAsync(y, 0, (size_t)out_size * sizeof(float), stream);
    gru_mfma<<<NBLK, 64, 0, stream>>>(x, cg, cs, W_ih, W_hh, b_ih, b_hh,
                                      W_out, b_out, y);
}

// Round 22
// 74.283 us; speedup vs baseline: 1.0419x; 1.0419x over previous
//
#include <hip/hip_runtime.h>

#define T_LEN 65536
#define C_CH 8
#define CLEN 16
#define NB 16
#define WIN (CLEN * NB)          // 256 steps per window
#define NBLK 2048                // 32 whi x 8 ch x 8 slot; 1 window per wave
#define SCANW 6                  // 384 bits scanned per window
#define MAXB 32                  // step-block size

typedef short bf16x8 __attribute__((ext_vector_type(8)));
typedef float f32x4 __attribute__((ext_vector_type(4)));
typedef unsigned int uint;
typedef uint u32x4 __attribute__((ext_vector_type(4)));
typedef unsigned long long u64;

#define MFMA32 __builtin_amdgcn_mfma_f32_16x16x32_bf16

#define SC_RZ 1.4426950408889634f   // log2(e): folded into r/z rows
#define SC_N  2.8853900817779268f   // 2*log2(e): folded into n rows

__device__ __forceinline__ uint f2bf(float f) {           // RNE float->bf16
    uint u = __float_as_uint(f);
    return (u + 0x7FFFu + ((u >> 16) & 1u)) >> 16;
}
__device__ __forceinline__ uint pk(float a, float b) {
    return f2bf(a) | (f2bf(b) << 16);
}
__device__ __forceinline__ uint cvtpk(float lo, float hi) {
    uint r;
    asm("v_cvt_pk_bf16_f32 %0, %1, %2" : "=v"(r) : "v"(lo), "v"(hi));
    return r;
}
// builtin exp2: compiler knows TRANS hazard (inline-asm version was R7's bug)
__device__ __forceinline__ float expneg(float x) { return __builtin_amdgcn_exp2f(-x); }
__device__ __forceinline__ bf16x8 mk8(uint a, uint b, uint c, uint d) {
    union { uint u[4]; bf16x8 v; } x;
    x.u[0] = a; x.u[1] = b; x.u[2] = c; x.u[3] = d;
    return x.v;
}
__device__ __forceinline__ bf16x8 q2b(u32x4 q) {
    union { u32x4 q; bf16x8 b; } u; u.q = q; return u.b;
}
__device__ __forceinline__ float rcpf(float v) { return __builtin_amdgcn_rcpf(v); }

// largest set-bit position p <= X in the 384-bit window mask; -1 if none.
// Wave-uniform inputs -> uniform branches, no divergence cost.
__device__ __forceinline__ int prev_start_le(u64 w0, u64 w1, u64 w2, u64 w3,
                                             u64 w4, u64 w5, int X) {
    auto msk = [](u64 w, int base, int X) -> u64 {
        if (X < base) return 0ull;
        int r = X - base;
        u64 m = (r >= 63) ? ~0ull : ((1ull << (r + 1)) - 1ull);
        return w & m;
    };
    u64 m5 = msk(w5, 320, X), m4 = msk(w4, 256, X), m3 = msk(w3, 192, X);
    u64 m2 = msk(w2, 128, X), m1 = msk(w1, 64, X),  m0 = msk(w0, 0, X);
    if (m5) return 320 + 63 - __builtin_clzll(m5);
    if (m4) return 256 + 63 - __builtin_clzll(m4);
    if (m3) return 192 + 63 - __builtin_clzll(m3);
    if (m2) return 128 + 63 - __builtin_clzll(m2);
    if (m1) return  64 + 63 - __builtin_clzll(m1);
    if (m0) return        63 - __builtin_clzll(m0);
    return -1;
}

// FINAL (R20 revert): (64,2) + AGPR-pinned weights + minimax repartition with
// the L0+1-first ladder (L0-first attempt in R21 regressed: extra full ladder
// pass for rare feasibility). Best measured: 74.9us.
__global__ __launch_bounds__(64, 2) void gru_mfma(
    const float* __restrict__ x,     // (T,10,8)
    const int*   __restrict__ cg,    // (T,8)
    const int*   __restrict__ cs,    // (T,8)
    const float* __restrict__ W_ih,  // (8,192,4)
    const float* __restrict__ W_hh,  // (8,192,64)
    const float* __restrict__ b_ih,  // (8,192)
    const float* __restrict__ b_hh,  // (8,192)
    const float* __restrict__ W_out, // (8,1,64)
    const float* __restrict__ b_out, // (8,)
    float* __restrict__ y)           // (T,)
{
    __shared__ u64 stw[SCANW], acw[SCANW];
    __shared__ int sb[NB + 1];
    __shared__ float yw[NB][MAXB + 1];
    __shared__ uint2 bxl[MAXB][NB];

    const int lane = threadIdx.x;
    const int l15 = lane & 15, l4 = lane >> 4;
    // decode: all 8 channels of one time-slot share an XCD (bid%8 = w%8)
    const int slot = blockIdx.x & 7;
    const int c    = (blockIdx.x >> 3) & 7;
    const int whi  = blockIdx.x >> 6;        // 0..31
    const int w    = whi * 8 + slot;         // window id 0..255
    const int RB   = w * WIN;

    // ---- cooperative scan of cs/cg bits ----
    for (int rr = 0; rr < SCANW; ++rr) {
        int t = RB + rr * 64 + lane;
        int sv = 0, av = 0;
        if (t < T_LEN) { sv = cs[t * C_CH + c]; av = cg[t * C_CH + c]; }
        u64 m1 = __ballot(sv == 1);
        u64 m2 = __ballot(av == 1);
        if (lane == 0) { stw[rr] = m1; acw[rr] = m2; }
    }
    __syncthreads();

    // ---- grid boundaries (also the fallback): sb[k] = first start >= RB+k*CLEN ----
    if (lane <= NB) {
        int rel = lane * CLEN;
        int q = rel >> 6, r0 = rel & 63;
        u64 m = stw[q] >> r0;
        int pos = -1;
        if (m) pos = rel + __ffsll(m) - 1;
        else {
            for (int q2 = q + 1; q2 < SCANW; ++q2)
                if (stw[q2]) { pos = (q2 << 6) + __ffsll(stw[q2]) - 1; break; }
        }
        int Sa;
        if (pos >= 0) Sa = RB + pos;
        else {  // ultra-rare fallback: serial scan past region
            int t = RB + SCANW * 64;
            while (t < T_LEN && cs[t * C_CH + c] != 1) ++t;
            Sa = t;
        }
        sb[lane] = min(Sa, T_LEN);
    }
    __syncthreads();

    // ---- minimax rebalance of interior boundaries (load-balance 16 chunks) ----
    {
        const int rel0  = sb[0]  - RB;
        const int rel16 = sb[NB] - RB;
        if (rel16 > rel0 && rel16 <= SCANW * 64 && rel0 < SCANW * 64) {
            const u64 w0 = stw[0], w1 = stw[1], w2 = stw[2];
            const u64 w3 = stw[3], w4 = stw[4], w5 = stw[5];
            const int span = rel16 - rel0;
            const int L0 = (span + 15) >> 4;
            int myb = 0;
            bool done = false;
#pragma unroll
            for (int a = 0; a < 4; ++a) {
                const int L = L0 + ((a == 0) ? 1 : (a == 1) ? 3 : (a == 2) ? 6 : 10);
                if (done) continue;
                int prev = rel0, mybt = 0;
                bool ok = true;
                for (int k = 1; k <= 15; ++k) {
                    int bk;
                    if (prev >= rel16) bk = rel16;
                    else {
                        int cap = min(prev + L, rel16);
                        int nb = prev_start_le(w0, w1, w2, w3, w4, w5, cap);
                        if (nb <= prev) { ok = false; nb = prev; }
                        bk = nb;
                    }
                    if (lane == k) mybt = bk;
                    prev = bk;
                }
                ok = ok && (rel16 - prev <= L);
                if (ok) { done = true; myb = mybt; }
            }
            __syncthreads();
            if (done && lane >= 1 && lane <= 15) sb[lane] = RB + myb;
        }
    }
    __syncthreads();

    const int S = sb[l15];
    const int len = sb[l15 + 1] - S;
    int Lmax = len;
#pragma unroll
    for (int o = 1; o < 16; o <<= 1) Lmax = max(Lmax, __shfl_xor(Lmax, o));

    // ---- A-fragments -> AGPRs (window constants), log2e pre-scaled ----
    const float* Wc = W_hh + c * 192 * 64;
    u32x4 AhA[12][2];
#pragma unroll
    for (int tm = 0; tm < 12; ++tm) {
        const float sc = (tm < 8) ? SC_RZ : SC_N;
#pragma unroll
        for (int kt = 0; kt < 2; ++kt) {
            const float* p = Wc + (16 * tm + l15) * 64 + 32 * kt + 4 * l4;
            float4 a = *(const float4*)p;
            float4 b = *(const float4*)(p + 16);
            AhA[tm][kt] = (u32x4){ pk(a.x * sc, a.y * sc), pk(a.z * sc, a.w * sc),
                                   pk(b.x * sc, b.y * sc), pk(b.z * sc, b.w * sc) };
            asm volatile("" : "+a"(AhA[tm][kt]));   // pin quad into AGPRs
        }
    }
    // W_out as a 13th A-tile (row 0 only): y_t = W_out . h_t via 2 MFMAs
    u32x4 WoA[2];
#pragma unroll
    for (int kt = 0; kt < 2; ++kt) {
        uint d0 = 0, d1 = 0, d2 = 0, d3 = 0;
        if (l15 == 0) {
            const float* wp = W_out + c * 64 + 32 * kt + 4 * l4;
            d0 = pk(wp[0], wp[1]);  d1 = pk(wp[2], wp[3]);
            d2 = pk(wp[16], wp[17]); d3 = pk(wp[18], wp[19]);
        }
        WoA[kt] = (u32x4){ d0, d1, d2, d3 };
        asm volatile("" : "+a"(WoA[kt]));
    }

    // W_ih cols (k=0..3) + ones-column bias at k=4: r/z merged b_ih+b_hh; n: b_ih
    uint Axd[12][2];
#pragma unroll
    for (int tm = 0; tm < 12; ++tm) {
        const float sc = (tm < 8) ? SC_RZ : SC_N;
        int row = 16 * tm + l15;
        uint d0 = 0, d1 = 0;
        if (l4 == 0) {
            float4 wi4 = *(const float4*)(W_ih + (c * 192 + row) * 4);
            d0 = pk(wi4.x * sc, wi4.y * sc);
            d1 = pk(wi4.z * sc, wi4.w * sc);
        } else if (l4 == 1) {
            float bias = (tm < 8) ? (b_ih[c * 192 + row] + b_hh[c * 192 + row]) * SC_RZ
                                  : b_ih[c * 192 + row] * SC_N;
            d0 = f2bf(bias);
        }
        Axd[tm][0] = d0; Axd[tm][1] = d1;
    }
    // n-gate b_hh as fp32 C-init (row = 4*l4+i, column-independent)
    f32x4 bhn4[4];
#pragma unroll
    for (int tn = 0; tn < 4; ++tn) {
        float4 v = *(const float4*)(b_hh + c * 192 + 128 + 16 * tn + 4 * l4);
        bhn4[tn] = (f32x4){v.x * SC_N, v.y * SC_N, v.z * SC_N, v.w * SC_N};
    }
    const float bo = b_out[c];

    // ---- state: bf16 B-frags ONLY (h_old re-expanded by shift; no fp32 h) ----
    uint B0[4], B1[4];
#pragma unroll
    for (int i = 0; i < 4; ++i) { B0[i] = 0u; B1[i] = 0u; }
    const uint bx_c0 = (l4 == 1) ? 0x00003F80u : 0u;  // bf16(1.0) at k=4
    const f32x4 z4 = {0.f, 0.f, 0.f, 0.f};

    for (int s0 = 0; s0 < Lmax; s0 += MAXB) {
        const int Lb = min(MAXB, Lmax - s0);

        // stage Bx payloads: bxl[s][b] = packed bf16 {x1..x4}(t = S_b+s0+s)
        const int npair = Lb * NB;
        for (int p = lane; p < npair; p += 64) {
            int s = p >> 4;
            int t = min(sb[p & 15] + s0 + s, T_LEN - 1);
            const float* xp = x + (size_t)t * 80 + 8 + c;
            bxl[s][p & 15] = make_uint2(pk(xp[0], xp[8]), pk(xp[16], xp[24]));
        }
        // per-lane reset mask for its column, this step-block
        int off = (S - RB) + s0;
        int q = off >> 6, r0 = off & 63;
        u64 w0s = (q < SCANW) ? stw[q] : 0ull;
        u64 w1s = (q + 1 < SCANW) ? stw[q + 1] : 0ull;
        u64 ms = (w0s >> r0) | (r0 ? (w1s << (64 - r0)) : 0ull);
        __syncthreads();

        // Bx register double-buffer: ds_read for step s+1 issues during step s
        uint2 bxn = bxl[0][l15];

        for (int s = 0; s < Lb; ++s) {
            const uint2 bxc = bxn;
            if (s + 1 < Lb) bxn = bxl[s + 1][l15];

            const bool rst = (ms >> s) & 1;
#pragma unroll
            for (int i = 0; i < 4; ++i) {
                B0[i] = rst ? 0u : B0[i];
                B1[i] = rst ? 0u : B1[i];
            }

            const bf16x8 Bx  = mk8((lane < 16) ? bxc.x : bx_c0,
                                   (lane < 16) ? bxc.y : 0u, 0u, 0u);
            const bf16x8 Bh0 = mk8(B0[0], B0[1], B0[2], B0[3]);
            const bf16x8 Bh1 = mk8(B1[0], B1[1], B1[2], B1[3]);

            uint nB[8];
#pragma unroll
            for (int tm = 0; tm < 4; ++tm) {
                const int tz = tm + 4, tn = tm + 8;
                f32x4 ar = MFMA32(mk8(Axd[tm][0], Axd[tm][1], 0u, 0u), Bx, z4, 0, 0, 0);
                ar = MFMA32(q2b(AhA[tm][0]), Bh0, ar, 0, 0, 0);
                ar = MFMA32(q2b(AhA[tm][1]), Bh1, ar, 0, 0, 0);
                f32x4 az = MFMA32(mk8(Axd[tz][0], Axd[tz][1], 0u, 0u), Bx, z4, 0, 0, 0);
                az = MFMA32(q2b(AhA[tz][0]), Bh0, az, 0, 0, 0);
                az = MFMA32(q2b(AhA[tz][1]), Bh1, az, 0, 0, 0);
                f32x4 gx = MFMA32(mk8(Axd[tn][0], Axd[tn][1], 0u, 0u), Bx, z4, 0, 0, 0);
                f32x4 gh = MFMA32(q2b(AhA[tn][0]), Bh0, bhn4[tm], 0, 0, 0);
                gh = MFMA32(q2b(AhA[tn][1]), Bh1, gh, 0, 0, 0);

                float hv[4];
#pragma unroll
                for (int i = 0; i < 4; ++i) {
                    // pre-activations pre-scaled by log2e (r/z) / 2log2e (n).
                    // Joint reciprocal (R15): 5 trans/element.
                    float Dr = 1.f + expneg(ar[i]);
                    float Dz = 1.f + expneg(az[i]);
                    float rc = rcpf(Dr * Dz);
                    float rr = rc * Dz;
                    float zz = rc * Dr;
                    float np2 = fmaf(rr, gh[i], gx[i]);
                    float nn = fmaf(2.f, rcpf(1.f + expneg(np2)), -1.f);
                    // h_old from the bf16 state frag (1-op expand)
                    const uint bd = (tm < 2) ? B0[2 * (tm & 1) + (i >> 1)]
                                             : B1[2 * (tm & 1) + (i >> 1)];
                    const float hold = __uint_as_float((i & 1) ? (bd & 0xFFFF0000u)
                                                               : (bd << 16));
                    float hh = fmaf(zz, hold - nn, nn);
                    hv[i] = hh;
                }
                nB[2 * tm]     = cvtpk(hv[0], hv[1]);
                nB[2 * tm + 1] = cvtpk(hv[2], hv[3]);
            }
            // D-layout == B-layout: tiles 0,1 -> Bh0; 2,3 -> Bh1
            B0[0] = nB[0]; B0[1] = nB[1]; B0[2] = nB[2]; B0[3] = nB[3];
            B1[0] = nB[4]; B1[1] = nB[5]; B1[2] = nB[6]; B1[3] = nB[7];

            // y_t = W_out . h_t via the 13th tile (row 0 -> lanes 0-15, reg 0)
            const bf16x8 Bh0n = mk8(B0[0], B0[1], B0[2], B0[3]);
            const bf16x8 Bh1n = mk8(B1[0], B1[1], B1[2], B1[3]);
            f32x4 y4 = MFMA32(q2b(WoA[0]), Bh0n, z4, 0, 0, 0);
            y4 = MFMA32(q2b(WoA[1]), Bh1n, y4, 0, 0, 0);
            if (lane < 16 && (s0 + s) < len) yw[lane][s] = y4[0];
        }
        __syncthreads();

        // write back: one coalesced atomic row per chunk (channels collide)
        for (int b = 0; b < NB; ++b) {
            int Sb = sb[b];
            int lenb = sb[b + 1] - Sb;
            int sg = s0 + lane;
            if (lane < Lb && sg < lenb) {
                int offa = (Sb - RB) + sg;
                int qa = offa >> 6;
                bool act;
                if (qa < SCANW) act = (acw[qa] >> (offa & 63)) & 1;
                else            act = cg[(Sb + sg) * C_CH + c] == 1;  // rare
                if (act) atomicAdd(&y[Sb + sg], yw[b][lane] + bo);
            }
        }
        __syncthreads();
    }
}

extern "C" void kernel_launch(void* const* d_in, const int* in_sizes, int n_in,
                              void* d_out, int out_size, void* d_ws, size_t ws_size,
                              hipStream_t stream) {
    const float* x     = (const float*)d_in[0];
    const int*   cg    = (const int*)  d_in[1];
    const int*   cs    = (const int*)  d_in[2];
    const float* W_ih  = (const float*)d_in[3];
    const float* W_hh  = (const float*)d_in[4];
    const float* b_ih  = (const float*)d_in[5];
    const float* b_hh  = (const float*)d_in[6];
    const float* W_out = (const float*)d_in[7];
    const float* b_out = (const float*)d_in[8];
    float* y = (float*)d_out;

    hipMemsetAsync(y, 0, (size_t)out_size * sizeof(float), stream);
    gru_mfma<<<NBLK, 64, 0, stream>>>(x, cg, cs, W_ih, W_hh, b_ih, b_hh,
                                      W_out, b_out, y);
}